// Round 7
// baseline (1889.206 us; speedup 1.0000x reference)
//
#include <hip/hip_runtime.h>
#include <math.h>

#define DT    0.01f
#define B_    64
#define S_    4096
#define I_    128
#define H_    256
#define O_    128

typedef _Float16 f16x8 __attribute__((ext_vector_type(8)));
typedef float    f32x4 __attribute__((ext_vector_type(4)));

// ---------------------------------------------------------------------------
// Kernel 1: xproj[b,t,j] = b[j] + sum_i x[b,t,i] * W[i,j]   (W rows 0..127)
// ---------------------------------------------------------------------------
#define RPB 64

__global__ __launch_bounds__(256, 2) void xproj_kernel(
    const float* __restrict__ x, const float* __restrict__ W,
    const float* __restrict__ bias, float* __restrict__ xp)
{
  __shared__ __align__(16) float xs[RPB][I_];
  const int j = threadIdx.x;

  float w[I_];
#pragma unroll
  for (int k = 0; k < I_; ++k) w[k] = W[k * H_ + j];
  const float bj = bias[j];

  const size_t row0 = (size_t)blockIdx.x * RPB;

  const float4* src4 = (const float4*)(x + row0 * I_);
  float4* xs4 = (float4*)&xs[0][0];
#pragma unroll
  for (int i = 0; i < (RPB * I_ / 4) / 256; ++i)
    xs4[j + i * 256] = src4[j + i * 256];
  __syncthreads();

  for (int r = 0; r < RPB; r += 4) {
    float a0 = bj, a1 = bj, a2 = bj, a3 = bj;
    const float4* r0 = (const float4*)xs[r + 0];
    const float4* r1 = (const float4*)xs[r + 1];
    const float4* r2 = (const float4*)xs[r + 2];
    const float4* r3 = (const float4*)xs[r + 3];
#pragma unroll
    for (int k4 = 0; k4 < I_ / 4; ++k4) {
      float4 v0 = r0[k4], v1 = r1[k4], v2 = r2[k4], v3 = r3[k4];
      a0 = fmaf(v0.x, w[4*k4+0], a0); a0 = fmaf(v0.y, w[4*k4+1], a0);
      a0 = fmaf(v0.z, w[4*k4+2], a0); a0 = fmaf(v0.w, w[4*k4+3], a0);
      a1 = fmaf(v1.x, w[4*k4+0], a1); a1 = fmaf(v1.y, w[4*k4+1], a1);
      a1 = fmaf(v1.z, w[4*k4+2], a1); a1 = fmaf(v1.w, w[4*k4+3], a1);
      a2 = fmaf(v2.x, w[4*k4+0], a2); a2 = fmaf(v2.y, w[4*k4+1], a2);
      a2 = fmaf(v2.z, w[4*k4+2], a2); a2 = fmaf(v2.w, w[4*k4+3], a2);
      a3 = fmaf(v3.x, w[4*k4+0], a3); a3 = fmaf(v3.y, w[4*k4+1], a3);
      a3 = fmaf(v3.z, w[4*k4+2], a3); a3 = fmaf(v3.w, w[4*k4+3], a3);
    }
    xp[(row0 + r + 0) * H_ + j] = a0;
    xp[(row0 + r + 1) * H_ + j] = a1;
    xp[(row0 + r + 2) * H_ + j] = a2;
    xp[(row0 + r + 3) * H_ + j] = a3;
  }
}

// ---------------------------------------------------------------------------
// Kernel 2: LTC recurrence via MFMA, 512 threads = 8 waves (2/SIMD).
// r6 structure (zero-redundancy update, xpre-seeded C-in, 16 MFMA/wave)
// PLUS:
//  - raw s_barrier with ONLY lgkmcnt(0) drained (ds-write visibility);
//    vmcnt is NOT drained, so global loads stay in flight across steps
//    (the __syncthreads vmcnt(0) drain put a full HBM round-trip ~900cy
//    on every step's critical path -> r6's 917cy step time).
//  - xp prefetched 2 steps deep in a rotating register pair; backend emits
//    counted vmcnt before use (~2 steps of slack covers HBM latency).
// ---------------------------------------------------------------------------
__global__ __launch_bounds__(512, 2) void ltc_main(
    const float* __restrict__ xp, const float* __restrict__ W,
    const float* __restrict__ tau, const float* __restrict__ A,
    const float* __restrict__ Wo, const float* __restrict__ bo,
    float* __restrict__ out)
{
  const int b  = blockIdx.x;
  const int t  = threadIdx.x;
  const int wv = t >> 6;       // 0..7
  const int l  = t & 63;
  const int g  = l >> 4;       // k-slice group 0..3
  const int c  = l & 15;       // col within 16-group
  const int s  = l >> 5;       // which col-group this lane keeps
  const int o  = wv * 32 + s * 16 + c;  // this lane's output (2 lanes/output)

  // B-fragments: 2 col-groups x 8 K-tiles, register-resident (64 VGPRs)
  f16x8 bw[2][8];
#pragma unroll
  for (int sg = 0; sg < 2; ++sg)
#pragma unroll
    for (int kt = 0; kt < 8; ++kt)
#pragma unroll
      for (int j = 0; j < 8; ++j)
        bw[sg][kt][j] =
            (_Float16)W[(I_ + kt * 32 + g * 8 + j) * H_ + (wv * 32 + sg * 16 + c)];

  __shared__ __align__(16) _Float16 hs[2][H_];
  __shared__ float hfin[H_];

  const float Aj   = A[o];
  const float itau = 1.0f / tau[o];
  const float dtA  = DT * Aj;
  const float base = 1.0f + DT * itau;

  const float* xprow = xp + (size_t)b * S_ * H_ + o;

  float h    = 0.0f;
  float xpre = xprow[0];        // step 0
  float xnxt = xprow[H_];       // step 1
  if (t < H_) hs[0][t] = (_Float16)0.0f;
  __syncthreads();

#define LTC_BODY(RB, WB, STEP)                                               \
  {                                                                          \
    const _Float16* hb = &hs[RB][g * 8];                                     \
    f16x8 a[8];                                                              \
    _Pragma("unroll")                                                        \
    for (int kt = 0; kt < 8; ++kt) a[kt] = *(const f16x8*)(hb + kt * 32);    \
    const int snext = ((STEP) + 2 < S_) ? (STEP) + 2 : (S_ - 1);             \
    const float xnew = xprow[(size_t)snext * H_];  /* 2-deep prefetch */     \
    f32x4 ac00 = {xpre, xpre, xpre, xpre};                                   \
    f32x4 ac01 = {0.f, 0.f, 0.f, 0.f};                                       \
    f32x4 ac10 = {xpre, xpre, xpre, xpre};                                   \
    f32x4 ac11 = {0.f, 0.f, 0.f, 0.f};                                       \
    __builtin_amdgcn_s_setprio(1);                                           \
    _Pragma("unroll")                                                        \
    for (int kt = 0; kt < 4; ++kt) {                                         \
      ac00 = __builtin_amdgcn_mfma_f32_16x16x32_f16(a[kt], bw[0][kt], ac00,  \
                                                    0, 0, 0);                \
      ac10 = __builtin_amdgcn_mfma_f32_16x16x32_f16(a[kt], bw[1][kt], ac10,  \
                                                    0, 0, 0);                \
      ac01 = __builtin_amdgcn_mfma_f32_16x16x32_f16(a[kt + 4], bw[0][kt + 4],\
                                                    ac01, 0, 0, 0);          \
      ac11 = __builtin_amdgcn_mfma_f32_16x16x32_f16(a[kt + 4], bw[1][kt + 4],\
                                                    ac11, 0, 0, 0);          \
    }                                                                        \
    __builtin_amdgcn_s_setprio(0);                                           \
    const float z0 = ac00[0] + ac01[0];                                      \
    const float z1 = ac10[0] + ac11[0];                                      \
    float z = (l & 32) ? z1 : z0;                                            \
    z = fminf(15.0f, fmaxf(-15.0f, z));                                      \
    const float E = __expf(2.0f * z);                                        \
    const float f = (E - 1.0f) * __builtin_amdgcn_rcpf(E + 1.0f);            \
    h = fmaf(dtA, f, h) * __builtin_amdgcn_rcpf(fmaf(DT, f, base));          \
    if (!(l & 16)) hs[WB][o] = (_Float16)h;                                  \
    xpre = xnxt;                                                             \
    xnxt = xnew;                                                             \
    asm volatile("s_waitcnt lgkmcnt(0)" ::: "memory");                       \
    __builtin_amdgcn_s_barrier();                                            \
    __builtin_amdgcn_sched_barrier(0);                                       \
  }

  for (int st = 0; st < S_; st += 2) {
    LTC_BODY(0, 1, st)
    LTC_BODY(1, 0, st + 1)
  }
#undef LTC_BODY

  // stage final f32 h, then fused output projection
  if (!(l & 16)) hfin[o] = h;
  __syncthreads();

  if (t < O_) {
    float accO = bo[t];
#pragma unroll 8
    for (int hh = 0; hh < H_; ++hh)
      accO = fmaf(hfin[hh], Wo[hh * O_ + t], accO);
    out[b * O_ + t] = accO;
  }
}

// ---------------------------------------------------------------------------
// Fallback (no workspace): proven structure with inline x-proj.
// ---------------------------------------------------------------------------
__global__ __launch_bounds__(1024) void ltc_inline(
    const float* __restrict__ x, const float* __restrict__ W,
    const float* __restrict__ bias, const float* __restrict__ tau,
    const float* __restrict__ A, const float* __restrict__ Wo,
    const float* __restrict__ bo, float* __restrict__ out)
{
  const int b = blockIdx.x;
  const int t = threadIdx.x;
  const int j = t & (H_ - 1);
  const int c = t >> 8;

  float wh[64], wx[32];
#pragma unroll
  for (int kk = 0; kk < 64; ++kk)
    wh[kk] = W[(I_ + c * 64 + kk) * H_ + j];
#pragma unroll
  for (int kk = 0; kk < 32; ++kk)
    wx[kk] = W[(c * 32 + kk) * H_ + j];

  __shared__ __align__(16) float hsf[H_];
  __shared__ __align__(16) float xsf[I_];
  __shared__ float ps[3][H_];

  float Aj = 0.f, itau = 0.f, bj = 0.f;
  if (c == 0) {
    Aj = A[j];
    itau = 1.0f / tau[j];
    bj = bias[j];
    hsf[j] = 0.0f;
  }
  const float4* xrow4 = (const float4*)(x + (size_t)b * S_ * I_);
  if (t < 32) ((float4*)xsf)[t] = xrow4[t];
  __syncthreads();

  for (int step = 0; step < S_; ++step) {
    float4 xnext4 = make_float4(0.f, 0.f, 0.f, 0.f);
    if (t < 32) {
      const int snext = (step + 1 < S_) ? step + 1 : step;
      xnext4 = xrow4[snext * 32 + t];
    }

    float acc = 0.0f;
#pragma unroll
    for (int kk = 0; kk < 64; kk += 4) {
      float4 h4 = *(const float4*)&hsf[c * 64 + kk];
      acc = fmaf(h4.x, wh[kk + 0], acc);
      acc = fmaf(h4.y, wh[kk + 1], acc);
      acc = fmaf(h4.z, wh[kk + 2], acc);
      acc = fmaf(h4.w, wh[kk + 3], acc);
    }
#pragma unroll
    for (int kk = 0; kk < 32; kk += 4) {
      float4 x4 = *(const float4*)&xsf[c * 32 + kk];
      acc = fmaf(x4.x, wx[kk + 0], acc);
      acc = fmaf(x4.y, wx[kk + 1], acc);
      acc = fmaf(x4.z, wx[kk + 2], acc);
      acc = fmaf(x4.w, wx[kk + 3], acc);
    }

    if (c) ps[c - 1][j] = acc;
    __syncthreads();

    if (t < 32) ((float4*)xsf)[t] = xnext4;
    if (c == 0) {
      const float z = acc + ps[0][j] + ps[1][j] + ps[2][j] + bj;
      const float f = tanhf(z);
      const float hj = hsf[j];
      hsf[j] = (hj + DT * f * Aj) / (1.0f + DT * (itau + f));
    }
    __syncthreads();
  }

  if (t < O_) {
    float acc = bo[t];
#pragma unroll 8
    for (int h = 0; h < H_; ++h)
      acc = fmaf(hsf[h], Wo[h * O_ + t], acc);
    out[b * O_ + t] = acc;
  }
}

// ---------------------------------------------------------------------------
extern "C" void kernel_launch(void* const* d_in, const int* in_sizes, int n_in,
                              void* d_out, int out_size, void* d_ws, size_t ws_size,
                              hipStream_t stream) {
  const float* x   = (const float*)d_in[0];
  const float* W   = (const float*)d_in[1];
  const float* b   = (const float*)d_in[2];
  const float* tau = (const float*)d_in[3];
  const float* A   = (const float*)d_in[4];
  const float* Wo  = (const float*)d_in[5];
  const float* bo  = (const float*)d_in[6];
  float* out = (float*)d_out;

  const size_t XP_BYTES = (size_t)B_ * S_ * H_ * sizeof(float);

  if (ws_size >= XP_BYTES) {
    float* xp = (float*)d_ws;
    hipLaunchKernelGGL(xproj_kernel, dim3((B_ * S_) / RPB), dim3(256), 0, stream,
                       x, W, b, xp);
    hipLaunchKernelGGL(ltc_main, dim3(B_), dim3(512), 0, stream,
                       xp, W, tau, A, Wo, bo, out);
  } else {
    hipLaunchKernelGGL(ltc_inline, dim3(B_), dim3(1024), 0, stream,
                       x, W, b, tau, A, Wo, bo, out);
  }
}